// Round 1
// baseline (7997.178 us; speedup 1.0000x reference)
//
#include <hip/hip_runtime.h>
#include <hip/hip_bf16.h>
#include <cstdint>
#include <cstddef>

#define B_  8
#define S_  1300
#define D_  1080
#define H_  12
#define DK_ 90
#define FF_ 3240
#define MROWS (B_*S_)   // 10400

// ============================= LayerNorm =============================
// one block per row; single pass sum/sumsq; row cached in LDS
__global__ __launch_bounds__(256) void ln_kernel(const float* __restrict__ x,
    const float* __restrict__ g, const float* __restrict__ b,
    float* __restrict__ y)
{
    __shared__ float xs[D_];
    __shared__ float red[8];
    const int row = blockIdx.x;
    const int tid = threadIdx.x;
    const float* xr = x + (size_t)row * D_;

    float s = 0.f, sq = 0.f;
    for (int d = tid; d < D_; d += 256) {
        float v = xr[d];
        xs[d] = v;
        s += v; sq += v * v;
    }
    // wave (64-lane) reduction
    #pragma unroll
    for (int off = 32; off > 0; off >>= 1) {
        s  += __shfl_down(s,  off, 64);
        sq += __shfl_down(sq, off, 64);
    }
    const int wave = tid >> 6, lane = tid & 63;
    if (lane == 0) { red[wave] = s; red[4 + wave] = sq; }
    __syncthreads();
    if (tid == 0) {
        float ts = 0.f, tq = 0.f;
        #pragma unroll
        for (int w = 0; w < 4; ++w) { ts += red[w]; tq += red[4 + w]; }
        red[0] = ts; red[4] = tq;
    }
    __syncthreads();
    const float mean = red[0] * (1.0f / D_);
    const float var  = red[4] * (1.0f / D_) - mean * mean;
    const float rstd = rsqrtf(var + 1e-5f);
    float* yr = y + (size_t)row * D_;
    for (int d = tid; d < D_; d += 256)
        yr[d] = (xs[d] - mean) * rstd * g[d] + b[d];
}

// ============================= SGEMM =============================
// C[M,N] = A[M,K] @ B[K,N]  (+ epilogue)
// MODE 0: C = acc + bias
// MODE 1: C = acc + bias + res
// MODE 2: C = silu(C_prev) * (acc + bias)     (in-place SwiGLU combine)
// 128x128 tile, BK=8, 256 threads, 8x8 per thread.
template<int MODE>
__global__ __launch_bounds__(256) void sgemm(const float* __restrict__ A,
    const float* __restrict__ Bm, const float* __restrict__ bias,
    const float* __restrict__ res, float* __restrict__ C,
    int M, int N, int K)
{
    __shared__ float As[8][128];
    __shared__ float Bs[8][128];

    const int tid = threadIdx.x;
    const int m0 = blockIdx.y * 128;
    const int n0 = blockIdx.x * 128;

    // global-load mapping
    const int arow  = tid >> 1;          // 0..127
    const int aquad = (tid & 1) * 4;     // 0 or 4
    const int brow  = tid >> 5;          // 0..7
    const int bcol  = (tid & 31) * 4;    // 0..124

    // compute mapping
    const int ty = tid >> 4;             // 0..15 -> m
    const int tx = tid & 15;             // 0..15 -> n
    const int mth = m0 + ty * 8;
    const int nth = n0 + tx * 8;

    float acc[8][8] = {};

    const int nk = K >> 3;               // K % 8 == 0 for all our shapes
    for (int kt = 0; kt < nk; ++kt) {
        const int k0 = kt << 3;
        float4 av, bv;
        const int am = m0 + arow;
        if (am < M) av = *(const float4*)(A + (size_t)am * K + k0 + aquad);
        else        av = make_float4(0.f, 0.f, 0.f, 0.f);
        const int bn4 = n0 + bcol;
        if (bn4 < N) bv = *(const float4*)(Bm + (size_t)(k0 + brow) * N + bn4);
        else         bv = make_float4(0.f, 0.f, 0.f, 0.f);

        __syncthreads();
        As[aquad + 0][arow] = av.x;
        As[aquad + 1][arow] = av.y;
        As[aquad + 2][arow] = av.z;
        As[aquad + 3][arow] = av.w;
        *(float4*)&Bs[brow][bcol] = bv;
        __syncthreads();

        #pragma unroll
        for (int kk = 0; kk < 8; ++kk) {
            float a[8], bfr[8];
            #pragma unroll
            for (int i = 0; i < 8; ++i) a[i]   = As[kk][ty * 8 + i];
            #pragma unroll
            for (int i = 0; i < 8; ++i) bfr[i] = Bs[kk][tx * 8 + i];
            #pragma unroll
            for (int i = 0; i < 8; ++i)
                #pragma unroll
                for (int j = 0; j < 8; ++j)
                    acc[i][j] += a[i] * bfr[j];
        }
    }

    // epilogue (N % 8 == 0 so the 8-wide row is all-in or all-out)
    if (nth < N) {
        #pragma unroll
        for (int i = 0; i < 8; ++i) {
            const int m = mth + i;
            if (m < M) {
                const size_t off = (size_t)m * N + nth;
                #pragma unroll
                for (int j = 0; j < 8; ++j) {
                    float val = acc[i][j] + bias[nth + j];
                    if (MODE == 1) val += res[off + j];
                    if (MODE == 2) {
                        const float prev = C[off + j];           // h1
                        const float sig  = 1.0f / (1.0f + __expf(-prev));
                        val = (prev * sig) * val;                // silu(h1)*h3
                    }
                    C[off + j] = val;
                }
            }
        }
    }
}

// ============================= RoPE =============================
// in-place on q and k; layout [B,S,H,DK]; rotate_half split at DK/2=45
__global__ __launch_bounds__(256) void rope_kernel(float* __restrict__ q,
    float* __restrict__ k, const float* __restrict__ cosb,
    const float* __restrict__ sinb, int total)
{
    const int p = blockIdx.x * 256 + threadIdx.x;
    if (p >= total) return;          // total = B*S*H*45
    const int d  = p % 45;
    int t = p / 45;
    const int h  = t % H_;  t /= H_;
    const int s  = t % S_;
    const int b  = t / S_;

    const size_t base = ((size_t)(b * S_ + s) * D_) + h * DK_;
    const float c1 = cosb[s * DK_ + d],      s1 = sinb[s * DK_ + d];
    const float c2 = cosb[s * DK_ + d + 45], s2 = sinb[s * DK_ + d + 45];

    const float q1 = q[base + d], q2 = q[base + d + 45];
    q[base + d]      = q1 * c1 - q2 * s1;
    q[base + d + 45] = q2 * c2 + q1 * s2;

    const float k1 = k[base + d], k2 = k[base + d + 45];
    k[base + d]      = k1 * c1 - k2 * s1;
    k[base + d + 45] = k2 * c2 + k1 * s2;
}

// ============================= Attention =============================
// Flash-style causal attention. One thread = one query row.
// q/o in registers (90 each); K/V staged in LDS tiles of 32 rows,
// processed in chunks of 16 with online softmax.
__global__ __launch_bounds__(256) void attn_kernel(const float* __restrict__ q,
    const float* __restrict__ k, const float* __restrict__ v,
    float* __restrict__ attn)
{
    __shared__ float Ks[32][96];   // row stride 96 floats = 384B (16B aligned)
    __shared__ float Vs[32][96];

    const int tid = threadIdx.x;
    const int qi  = blockIdx.x * 256 + tid;
    const int bh  = blockIdx.y;
    const int b   = bh / H_;
    const int h   = bh % H_;
    const bool active = (qi < S_);
    const float scale = rsqrtf((float)DK_);

    const float* qptr = q + ((size_t)(b * S_ + (active ? qi : 0)) * D_ + h * DK_);
    float qreg[DK_], o[DK_];
    #pragma unroll
    for (int d = 0; d < DK_; ++d) { qreg[d] = qptr[d]; o[d] = 0.f; }

    float m = -1e30f, l = 0.f;

    const int qmax   = min(S_ - 1, (int)blockIdx.x * 256 + 255);
    const int ntiles = qmax / 32 + 1;

    for (int kt = 0; kt < ntiles; ++kt) {
        __syncthreads();
        // stage 32 rows of K and V (float2 loads; DK=90 -> 45 float2/row)
        for (int idx = tid; idx < 32 * 45; idx += 256) {
            const int r = idx / 45;
            const int c = idx - r * 45;
            const int krow = kt * 32 + r;
            const int safe = (krow < S_) ? krow : 0;
            const size_t g = ((size_t)(b * S_ + safe) * D_ + h * DK_) + c * 2;
            float2 kv = *(const float2*)(k + g);
            float2 vv = *(const float2*)(v + g);
            if (krow >= S_) { kv = make_float2(0.f, 0.f); vv = make_float2(0.f, 0.f); }
            *(float2*)&Ks[r][c * 2] = kv;
            *(float2*)&Vs[r][c * 2] = vv;
        }
        __syncthreads();

        #pragma unroll
        for (int c = 0; c < 2; ++c) {
            float s[16];
            float tmax = m;
            #pragma unroll
            for (int j = 0; j < 16; ++j) {
                const int jj = c * 16 + j;
                float acc = 0.f;
                #pragma unroll
                for (int d = 0; d < DK_; ++d) acc += qreg[d] * Ks[jj][d];
                acc *= scale;
                const int kidx = kt * 32 + jj;
                const bool valid = active && (kidx <= qi);
                s[j] = valid ? acc : -1e30f;
                tmax = fmaxf(tmax, s[j]);
            }
            const float resc = __expf(m - tmax);   // ==1 if unchanged
            m = tmax;
            l *= resc;
            #pragma unroll
            for (int d = 0; d < DK_; ++d) o[d] *= resc;
            #pragma unroll
            for (int j = 0; j < 16; ++j) {
                const float p = (s[j] > -1e29f) ? __expf(s[j] - m) : 0.f;
                l += p;
                const int jj = c * 16 + j;
                #pragma unroll
                for (int d = 0; d < DK_; ++d) o[d] += p * Vs[jj][d];
            }
        }
    }

    if (active) {
        const float inv = 1.0f / l;
        float* op = attn + ((size_t)(b * S_ + qi) * D_ + h * DK_);
        #pragma unroll
        for (int d = 0; d < DK_; ++d) op[d] = o[d] * inv;
    }
}

// ============================= launch =============================
extern "C" void kernel_launch(void* const* d_in, const int* in_sizes, int n_in,
                              void* d_out, int out_size, void* d_ws, size_t ws_size,
                              hipStream_t stream)
{
    const float* x    = (const float*)d_in[0];
    // d_in[1] = mask (causal tril, implemented directly)
    const float* Wq   = (const float*)d_in[2];
    const float* bq   = (const float*)d_in[3];
    const float* Wk   = (const float*)d_in[4];
    const float* bk   = (const float*)d_in[5];
    const float* Wv   = (const float*)d_in[6];
    const float* bv   = (const float*)d_in[7];
    const float* Wo   = (const float*)d_in[8];
    const float* bo   = (const float*)d_in[9];
    const float* W1   = (const float*)d_in[10];
    const float* b1   = (const float*)d_in[11];
    const float* W2   = (const float*)d_in[12];
    const float* b2   = (const float*)d_in[13];
    const float* W3   = (const float*)d_in[14];
    const float* b3   = (const float*)d_in[15];
    const float* ln1g = (const float*)d_in[16];
    const float* ln1b = (const float*)d_in[17];
    const float* ln2g = (const float*)d_in[18];
    const float* ln2b = (const float*)d_in[19];
    const float* rc   = (const float*)d_in[20];
    const float* rs   = (const float*)d_in[21];
    float* out = (float*)d_out;
    float* ws  = (float*)d_ws;

    const size_t N1 = (size_t)MROWS * D_;   // 11,232,000 floats
    float* x2 = ws;                          // LN output (reused for LN2)
    float* qb = ws + N1;                     // q; later reused as x1
    float* kb = ws + 2 * N1;                 // k; later start of FF hidden (3*N1 = M*FF)
    float* vb = ws + 3 * N1;                 // v
    float* ab = ws + 4 * N1;                 // attn out
    float* x1 = qb;
    float* hb = kb;
    // ws requirement: 5*N1*4 = ~225 MB

    const dim3 blk(256);
    const dim3 gD((D_ + 127) / 128, (MROWS + 127) / 128);    // 9 x 82
    const dim3 gF((FF_ + 127) / 128, (MROWS + 127) / 128);   // 26 x 82

    // 1) LN1
    ln_kernel<<<MROWS, blk, 0, stream>>>(x, ln1g, ln1b, x2);
    // 2) Q/K/V projections
    sgemm<0><<<gD, blk, 0, stream>>>(x2, Wq, bq, nullptr, qb, MROWS, D_, D_);
    sgemm<0><<<gD, blk, 0, stream>>>(x2, Wk, bk, nullptr, kb, MROWS, D_, D_);
    sgemm<0><<<gD, blk, 0, stream>>>(x2, Wv, bv, nullptr, vb, MROWS, D_, D_);
    // 3) RoPE on q,k in place
    {
        const int total = B_ * S_ * H_ * (DK_ / 2);          // 5,616,000
        rope_kernel<<<(total + 255) / 256, blk, 0, stream>>>(qb, kb, rc, rs, total);
    }
    // 4) causal flash attention -> ab
    {
        const dim3 gA((S_ + 255) / 256, B_ * H_);            // 6 x 96
        attn_kernel<<<gA, blk, 0, stream>>>(qb, kb, vb, ab);
    }
    // 5) O-projection + residual: x1 = x + ab@Wo + bo   (x1 overwrites qb)
    sgemm<1><<<gD, blk, 0, stream>>>(ab, Wo, bo, x, x1, MROWS, D_, D_);
    // 6) LN2
    ln_kernel<<<MROWS, blk, 0, stream>>>(x1, ln2g, ln2b, x2);
    // 7) FF: h1 = x2@W1 + b1  (hb spans kb..ab, exactly M*FF floats)
    sgemm<0><<<gF, blk, 0, stream>>>(x2, W1, b1, nullptr, hb, MROWS, FF_, D_);
    // 8) h = silu(h1) * (x2@W3 + b3), in place
    sgemm<2><<<gF, blk, 0, stream>>>(x2, W3, b3, nullptr, hb, MROWS, FF_, D_);
    // 9) out = x1 + h@W2 + b2
    sgemm<1><<<gD, blk, 0, stream>>>(hb, W2, b2, x1, out, MROWS, D_, FF_);
}

// Round 2
// 6989.827 us; speedup vs baseline: 1.1441x; 1.1441x over previous
//
#include <hip/hip_runtime.h>
#include <hip/hip_bf16.h>
#include <cstdint>
#include <cstddef>

#define B_  8
#define S_  1300
#define D_  1080
#define H_  12
#define DK_ 90
#define FF_ 3240
#define MROWS (B_*S_)   // 10400

// ============================= LayerNorm =============================
__global__ __launch_bounds__(256) void ln_kernel(const float* __restrict__ x,
    const float* __restrict__ g, const float* __restrict__ b,
    float* __restrict__ y)
{
    __shared__ float xs[D_];
    __shared__ float red[8];
    const int row = blockIdx.x;
    const int tid = threadIdx.x;
    const float* xr = x + (size_t)row * D_;

    float s = 0.f, sq = 0.f;
    for (int d = tid; d < D_; d += 256) {
        float v = xr[d];
        xs[d] = v;
        s += v; sq += v * v;
    }
    #pragma unroll
    for (int off = 32; off > 0; off >>= 1) {
        s  += __shfl_down(s,  off, 64);
        sq += __shfl_down(sq, off, 64);
    }
    const int wave = tid >> 6, lane = tid & 63;
    if (lane == 0) { red[wave] = s; red[4 + wave] = sq; }
    __syncthreads();
    if (tid == 0) {
        float ts = 0.f, tq = 0.f;
        #pragma unroll
        for (int w = 0; w < 4; ++w) { ts += red[w]; tq += red[4 + w]; }
        red[0] = ts; red[4] = tq;
    }
    __syncthreads();
    const float mean = red[0] * (1.0f / D_);
    const float var  = red[4] * (1.0f / D_) - mean * mean;
    const float rstd = rsqrtf(var + 1e-5f);
    float* yr = y + (size_t)row * D_;
    for (int d = tid; d < D_; d += 256)
        yr[d] = (xs[d] - mean) * rstd * g[d] + b[d];
}

// ============================= SGEMM =============================
// MODE 0: C = acc + bias ; MODE 1: += res ; MODE 2: C = silu(C_prev)*(acc+bias)
template<int MODE>
__global__ __launch_bounds__(256) void sgemm(const float* __restrict__ A,
    const float* __restrict__ Bm, const float* __restrict__ bias,
    const float* __restrict__ res, float* __restrict__ C,
    int M, int N, int K)
{
    __shared__ float As[8][128];
    __shared__ float Bs[8][128];

    const int tid = threadIdx.x;
    const int m0 = blockIdx.y * 128;
    const int n0 = blockIdx.x * 128;

    const int arow  = tid >> 1;
    const int aquad = (tid & 1) * 4;
    const int brow  = tid >> 5;
    const int bcol  = (tid & 31) * 4;

    const int ty = tid >> 4;
    const int tx = tid & 15;
    const int mth = m0 + ty * 8;
    const int nth = n0 + tx * 8;

    float acc[8][8] = {};

    const int nk = K >> 3;
    for (int kt = 0; kt < nk; ++kt) {
        const int k0 = kt << 3;
        float4 av, bv;
        const int am = m0 + arow;
        if (am < M) av = *(const float4*)(A + (size_t)am * K + k0 + aquad);
        else        av = make_float4(0.f, 0.f, 0.f, 0.f);
        const int bn4 = n0 + bcol;
        if (bn4 < N) bv = *(const float4*)(Bm + (size_t)(k0 + brow) * N + bn4);
        else         bv = make_float4(0.f, 0.f, 0.f, 0.f);

        __syncthreads();
        As[aquad + 0][arow] = av.x;
        As[aquad + 1][arow] = av.y;
        As[aquad + 2][arow] = av.z;
        As[aquad + 3][arow] = av.w;
        *(float4*)&Bs[brow][bcol] = bv;
        __syncthreads();

        #pragma unroll
        for (int kk = 0; kk < 8; ++kk) {
            float a[8], bfr[8];
            #pragma unroll
            for (int i = 0; i < 8; ++i) a[i]   = As[kk][ty * 8 + i];
            #pragma unroll
            for (int i = 0; i < 8; ++i) bfr[i] = Bs[kk][tx * 8 + i];
            #pragma unroll
            for (int i = 0; i < 8; ++i)
                #pragma unroll
                for (int j = 0; j < 8; ++j)
                    acc[i][j] += a[i] * bfr[j];
        }
    }

    if (nth < N) {
        #pragma unroll
        for (int i = 0; i < 8; ++i) {
            const int m = mth + i;
            if (m < M) {
                const size_t off = (size_t)m * N + nth;
                #pragma unroll
                for (int j = 0; j < 8; ++j) {
                    float val = acc[i][j] + bias[nth + j];
                    if (MODE == 1) val += res[off + j];
                    if (MODE == 2) {
                        const float prev = C[off + j];
                        const float sig  = 1.0f / (1.0f + __expf(-prev));
                        val = (prev * sig) * val;
                    }
                    C[off + j] = val;
                }
            }
        }
    }
}

// ============================= RoPE =============================
__global__ __launch_bounds__(256) void rope_kernel(float* __restrict__ q,
    float* __restrict__ k, const float* __restrict__ cosb,
    const float* __restrict__ sinb, int total)
{
    const int p = blockIdx.x * 256 + threadIdx.x;
    if (p >= total) return;
    const int d  = p % 45;
    int t = p / 45;
    const int h  = t % H_;  t /= H_;
    const int s  = t % S_;
    const int b  = t / S_;

    const size_t base = ((size_t)(b * S_ + s) * D_) + h * DK_;
    const float c1 = cosb[s * DK_ + d],      s1 = sinb[s * DK_ + d];
    const float c2 = cosb[s * DK_ + d + 45], s2 = sinb[s * DK_ + d + 45];

    const float q1 = q[base + d], q2 = q[base + d + 45];
    q[base + d]      = q1 * c1 - q2 * s1;
    q[base + d + 45] = q2 * c2 + q1 * s2;

    const float k1 = k[base + d], k2 = k[base + d + 45];
    k[base + d]      = k1 * c1 - k2 * s1;
    k[base + d + 45] = k2 * c2 + k1 * s2;
}

// ============================= Attention =============================
// Flash-style causal attention, 2 lanes per query row.
// Lane pair (2t, 2t+1) owns query qi = 11*t + blockIdx.x; parity selects
// head-dim half [48p, 48p+48) (DK=90 padded to 96 in LDS with zeros).
// Per-thread state: q[48] + o[48] -> no spill. QK partials combined via
// __shfl_xor(.,1). K/V staged in LDS 32-row tiles, float4 broadcast reads.
#define TK 32
__global__ __launch_bounds__(256) void attn_kernel(const float* __restrict__ q,
    const float* __restrict__ k, const float* __restrict__ v,
    float* __restrict__ attn)
{
    __shared__ float Ks[TK][96];
    __shared__ float Vs[TK][96];

    const int tid = threadIdx.x;
    const int bx  = blockIdx.x;         // 0..10
    const int bh  = blockIdx.y;
    const int b   = bh / H_;
    const int h   = bh % H_;
    const int t   = tid >> 1;           // pair index 0..127
    const int p   = tid & 1;            // dim-half parity
    const int qi  = 11 * t + bx;        // interleaved -> identical work/block
    const bool active = (qi < S_);
    const float scale = rsqrtf((float)DK_);
    // wave-uniform max query index (last lane of this wave's pairs)
    const int wqmax = 11 * ((tid | 63) >> 1) + bx;

    // load q fragment (this lane's 48-dim half; zero-pad beyond 90)
    float qreg[48];
    {
        const size_t base = ((size_t)(b * S_ + (active ? qi : 0)) * D_) + h * DK_ + p * 48;
        const int nval = p ? 42 : 48;   // p=1 half holds dims 48..89 (42 real)
        #pragma unroll
        for (int c = 0; c < 24; ++c) {
            float2 val = make_float2(0.f, 0.f);
            if (2 * c < nval) val = *(const float2*)(q + base + 2 * c);
            qreg[2 * c] = val.x; qreg[2 * c + 1] = val.y;
        }
    }
    float o[48];
    #pragma unroll
    for (int d = 0; d < 48; ++d) o[d] = 0.f;
    float m = -1e30f, l = 0.f;

    const int ntiles = (S_ + TK - 1) / TK;   // 41
    for (int kt = 0; kt < ntiles; ++kt) {
        __syncthreads();
        // stage K,V: 32 rows x 48 float2 (cols 90..95 zeroed)
        for (int idx = tid; idx < TK * 48; idx += 256) {
            const int r = idx / 48, c = idx - (idx / 48) * 48;
            const int krow = kt * TK + r;
            float2 kv = make_float2(0.f, 0.f), vv = make_float2(0.f, 0.f);
            if (krow < S_ && c < 45) {
                const size_t g = ((size_t)(b * S_ + krow) * D_) + h * DK_ + 2 * c;
                kv = *(const float2*)(k + g);
                vv = *(const float2*)(v + g);
            }
            *(float2*)&Ks[r][2 * c] = kv;
            *(float2*)&Vs[r][2 * c] = vv;
        }
        __syncthreads();
        if (kt * TK > wqmax) continue;  // wave-uniform skip (barriers still hit)

        #pragma unroll
        for (int cj = 0; cj < 4; ++cj) {   // 4 chunks of 8 keys
            float s[8];
            float tmax = m;
            #pragma unroll
            for (int j = 0; j < 8; ++j) {
                const int jj = cj * 8 + j;
                float acc = 0.f;
                const float4* kr = (const float4*)&Ks[jj][48 * p];
                #pragma unroll
                for (int c = 0; c < 12; ++c) {
                    const float4 kv = kr[c];
                    acc += qreg[4*c]   * kv.x + qreg[4*c+1] * kv.y
                         + qreg[4*c+2] * kv.z + qreg[4*c+3] * kv.w;
                }
                acc += __shfl_xor(acc, 1, 64);   // combine dim halves
                acc *= scale;
                const int kidx = kt * TK + jj;
                s[j] = (active && kidx <= qi) ? acc : -1e30f;
                tmax = fmaxf(tmax, s[j]);
            }
            const float resc = __expf(m - tmax);
            m = tmax;
            l *= resc;
            #pragma unroll
            for (int d = 0; d < 48; ++d) o[d] *= resc;
            #pragma unroll
            for (int j = 0; j < 8; ++j) {
                const float pj = (s[j] > -1e29f) ? __expf(s[j] - m) : 0.f;
                l += pj;
                const int jj = cj * 8 + j;
                const float4* vr = (const float4*)&Vs[jj][48 * p];
                #pragma unroll
                for (int c = 0; c < 12; ++c) {
                    const float4 vv = vr[c];
                    o[4*c]   += pj * vv.x; o[4*c+1] += pj * vv.y;
                    o[4*c+2] += pj * vv.z; o[4*c+3] += pj * vv.w;
                }
            }
        }
    }

    if (active) {
        const float inv = 1.0f / l;
        const size_t base = ((size_t)(b * S_ + qi) * D_) + h * DK_ + p * 48;
        const int nval = p ? 42 : 48;
        #pragma unroll
        for (int c = 0; c < 24; ++c) {
            if (2 * c < nval) {
                float2 val = make_float2(o[2*c] * inv, o[2*c+1] * inv);
                *(float2*)(attn + base + 2 * c) = val;
            }
        }
    }
}

// ============================= launch =============================
extern "C" void kernel_launch(void* const* d_in, const int* in_sizes, int n_in,
                              void* d_out, int out_size, void* d_ws, size_t ws_size,
                              hipStream_t stream)
{
    const float* x    = (const float*)d_in[0];
    const float* Wq   = (const float*)d_in[2];
    const float* bq   = (const float*)d_in[3];
    const float* Wk   = (const float*)d_in[4];
    const float* bk   = (const float*)d_in[5];
    const float* Wv   = (const float*)d_in[6];
    const float* bv   = (const float*)d_in[7];
    const float* Wo   = (const float*)d_in[8];
    const float* bo   = (const float*)d_in[9];
    const float* W1   = (const float*)d_in[10];
    const float* b1   = (const float*)d_in[11];
    const float* W2   = (const float*)d_in[12];
    const float* b2   = (const float*)d_in[13];
    const float* W3   = (const float*)d_in[14];
    const float* b3   = (const float*)d_in[15];
    const float* ln1g = (const float*)d_in[16];
    const float* ln1b = (const float*)d_in[17];
    const float* ln2g = (const float*)d_in[18];
    const float* ln2b = (const float*)d_in[19];
    const float* rc   = (const float*)d_in[20];
    const float* rs   = (const float*)d_in[21];
    float* out = (float*)d_out;
    float* ws  = (float*)d_ws;

    const size_t N1 = (size_t)MROWS * D_;
    float* x2 = ws;
    float* qb = ws + N1;
    float* kb = ws + 2 * N1;
    float* vb = ws + 3 * N1;
    float* ab = ws + 4 * N1;
    float* x1 = qb;
    float* hb = kb;   // M*FF floats spanning kb..ab

    const dim3 blk(256);
    const dim3 gD((D_ + 127) / 128, (MROWS + 127) / 128);
    const dim3 gF((FF_ + 127) / 128, (MROWS + 127) / 128);

    ln_kernel<<<MROWS, blk, 0, stream>>>(x, ln1g, ln1b, x2);
    sgemm<0><<<gD, blk, 0, stream>>>(x2, Wq, bq, nullptr, qb, MROWS, D_, D_);
    sgemm<0><<<gD, blk, 0, stream>>>(x2, Wk, bk, nullptr, kb, MROWS, D_, D_);
    sgemm<0><<<gD, blk, 0, stream>>>(x2, Wv, bv, nullptr, vb, MROWS, D_, D_);
    {
        const int total = B_ * S_ * H_ * (DK_ / 2);
        rope_kernel<<<(total + 255) / 256, blk, 0, stream>>>(qb, kb, rc, rs, total);
    }
    {
        const dim3 gA(11, B_ * H_);   // 11 blocks x 128 interleaved queries
        attn_kernel<<<gA, blk, 0, stream>>>(qb, kb, vb, ab);
    }
    sgemm<1><<<gD, blk, 0, stream>>>(ab, Wo, bo, x, x1, MROWS, D_, D_);
    ln_kernel<<<MROWS, blk, 0, stream>>>(x1, ln2g, ln2b, x2);
    sgemm<0><<<gF, blk, 0, stream>>>(x2, W1, b1, nullptr, hb, MROWS, FF_, D_);
    sgemm<2><<<gF, blk, 0, stream>>>(x2, W3, b3, nullptr, hb, MROWS, FF_, D_);
    sgemm<1><<<gD, blk, 0, stream>>>(hb, W2, b2, x1, out, MROWS, D_, FF_);
}

// Round 4
// 3308.688 us; speedup vs baseline: 2.4170x; 2.1126x over previous
//
#include <hip/hip_runtime.h>
#include <hip/hip_bf16.h>
#include <cstdint>
#include <cstddef>

#define B_  8
#define S_  1300
#define D_  1080
#define H_  12
#define DK_ 90
#define FF_ 3240
#define MROWS (B_*S_)   // 10400
#define KP1 1088        // 1080 padded to /32
#define KP2 3264        // 3240 padded to /32

typedef __hip_bfloat16 bf16;
typedef __bf16 bf16x8 __attribute__((ext_vector_type(8)));
typedef float  f32x4  __attribute__((ext_vector_type(4)));

__device__ __forceinline__ void gload16(const void* g, void* l) {
    __builtin_amdgcn_global_load_lds((const __attribute__((address_space(1))) void*)g,
                                     (__attribute__((address_space(3))) void*)l, 16, 0, 0);
}

// ================== zero pad columns [D_, KP1) of a bf16 [MROWS, KP1] buffer ==================
__global__ __launch_bounds__(256) void zero_pads(bf16* __restrict__ buf)
{
    const int idx = blockIdx.x * 256 + threadIdx.x;   // MROWS*8 items
    if (idx >= MROWS * (KP1 - D_)) return;
    const int row = idx >> 3, col = D_ + (idx & 7);
    buf[(size_t)row * KP1 + col] = __float2bfloat16(0.f);
}

// ===================== weight cast + transpose =====================
// W fp32 [K,N] -> WT bf16 [N,KP], zero-padded for k in [K,KP)
__global__ __launch_bounds__(256) void castT(const float* __restrict__ W,
    bf16* __restrict__ WT, int K, int N, int KP)
{
    __shared__ unsigned short t[32][33];
    const int tx = threadIdx.x & 31, ty = threadIdx.x >> 5;
    const int k0 = blockIdx.x * 32, n0 = blockIdx.y * 32;
    #pragma unroll
    for (int i = 0; i < 4; ++i) {
        const int k = k0 + ty + 8 * i;
        const int n = n0 + tx;
        float v = (k < K && n < N) ? W[(size_t)k * N + n] : 0.f;
        bf16 bv = __float2bfloat16(v);
        t[ty + 8 * i][tx] = *(unsigned short*)&bv;
    }
    __syncthreads();
    #pragma unroll
    for (int i = 0; i < 4; ++i) {
        const int n = n0 + ty + 8 * i;
        const int kk = k0 + tx;
        if (n < N && kk < KP) *(unsigned short*)&WT[(size_t)n * KP + kk] = t[tx][ty + 8 * i];
    }
}

// ============================= LayerNorm =============================
// fp32 in -> bf16 out, row stride KP1 (pads zeroed separately by zero_pads)
__global__ __launch_bounds__(256) void ln_kernel(const float* __restrict__ x,
    const float* __restrict__ g, const float* __restrict__ b,
    bf16* __restrict__ y)
{
    __shared__ float xs[D_];
    __shared__ float red[8];
    const int row = blockIdx.x;
    const int tid = threadIdx.x;
    const float* xr = x + (size_t)row * D_;

    float s = 0.f, sq = 0.f;
    for (int d = tid; d < D_; d += 256) {
        float v = xr[d];
        xs[d] = v;
        s += v; sq += v * v;
    }
    #pragma unroll
    for (int off = 32; off > 0; off >>= 1) {
        s  += __shfl_down(s,  off, 64);
        sq += __shfl_down(sq, off, 64);
    }
    const int wave = tid >> 6, lane = tid & 63;
    if (lane == 0) { red[wave] = s; red[4 + wave] = sq; }
    __syncthreads();
    if (tid == 0) {
        float ts = 0.f, tq = 0.f;
        #pragma unroll
        for (int w = 0; w < 4; ++w) { ts += red[w]; tq += red[4 + w]; }
        red[0] = ts; red[4] = tq;
    }
    __syncthreads();
    const float mean = red[0] * (1.0f / D_);
    const float var  = red[4] * (1.0f / D_) - mean * mean;
    const float rstd = rsqrtf(var + 1e-5f);
    bf16* yr = y + (size_t)row * KP1;
    for (int d = tid; d < D_; d += 256)
        yr[d] = __float2bfloat16((xs[d] - mean) * rstd * g[d] + b[d]);
}

// ============================= bf16 MFMA GEMM =============================
// C[M,N] = A[M,KP](bf16) @ BT[N,KP]^T(bf16) + epilogue.  KP % 32 == 0.
// MODE 0: Cf = acc + bias                (fp32 out)
// MODE 1: Cf = acc + bias + res          (fp32 out)
// MODE 2: Cb = silu(Cb_prev)*(acc+bias)  (bf16 in/out, in place)
// MODE 3: Cb = acc + bias                (bf16 out)
// bf16 modes write ZERO for n in [N, NP)  (keeps k-pads of downstream A clean).
template<int MODE>
__global__ __launch_bounds__(256) void gemm_bf16(
    const bf16* __restrict__ A, const bf16* __restrict__ BT,
    const float* __restrict__ bias, const float* __restrict__ res,
    float* __restrict__ Cf, bf16* __restrict__ Cb,
    int M, int N, int KP, int LDC, int NP)
{
    __shared__ unsigned short As[128 * 32];  // [m][k], contiguous (global_load_lds order)
    __shared__ unsigned short Bs[128 * 32];  // [n][k]

    const int tid = threadIdx.x;
    const int w = tid >> 6, l = tid & 63;
    const int m0 = blockIdx.y * 128, n0 = blockIdx.x * 128;

    const int rs = w * 16 + (l >> 2);
    const int kc = (l & 3) * 8;
    const int ar0 = min(m0 + rs,      M - 1);
    const int ar1 = min(m0 + rs + 64, M - 1);
    const int br0 = min(n0 + rs,      N - 1);
    const int br1 = min(n0 + rs + 64, N - 1);

    const int wm = (w >> 1) * 64, wn = (w & 1) * 64;
    const int lr = l & 15, kq = l >> 4;

    const unsigned short* aptr[4];
    const unsigned short* bptr[4];
    #pragma unroll
    for (int i = 0; i < 4; ++i) {
        aptr[i] = &As[(wm + i * 16 + lr) * 32 + kq * 8];
        bptr[i] = &Bs[(wn + i * 16 + lr) * 32 + kq * 8];
    }

    f32x4 acc[4][4] = {};

    const int nkt = KP >> 5;
    for (int kt = 0; kt < nkt; ++kt) {
        const int k0 = kt << 5;
        __syncthreads();
        gload16(A  + (size_t)ar0 * KP + k0 + kc, &As[w * 512]);
        gload16(A  + (size_t)ar1 * KP + k0 + kc, &As[2048 + w * 512]);
        gload16(BT + (size_t)br0 * KP + k0 + kc, &Bs[w * 512]);
        gload16(BT + (size_t)br1 * KP + k0 + kc, &Bs[2048 + w * 512]);
        __syncthreads();

        bf16x8 af[4], bv[4];
        #pragma unroll
        for (int i = 0; i < 4; ++i) af[i] = *(const bf16x8*)aptr[i];
        #pragma unroll
        for (int j = 0; j < 4; ++j) bv[j] = *(const bf16x8*)bptr[j];
        #pragma unroll
        for (int i = 0; i < 4; ++i)
            #pragma unroll
            for (int j = 0; j < 4; ++j)
                acc[i][j] = __builtin_amdgcn_mfma_f32_16x16x32_bf16(af[i], bv[j], acc[i][j], 0, 0, 0);
    }

    // epilogue: C/D layout col=lane&15, row=(lane>>4)*4+reg
    #pragma unroll
    for (int j = 0; j < 4; ++j) {
        const int n = n0 + wn + j * 16 + lr;
        if (n >= NP) continue;
        const bool real = (n < N);
        const float bn = real ? bias[n] : 0.f;
        #pragma unroll
        for (int i = 0; i < 4; ++i) {
            const int rowb = m0 + wm + i * 16 + kq * 4;
            #pragma unroll
            for (int r = 0; r < 4; ++r) {
                const int m = rowb + r;
                if (m < M) {
                    const size_t off = (size_t)m * LDC + n;
                    float val = acc[i][j][r] + bn;
                    if (MODE == 0) Cf[off] = val;
                    if (MODE == 1) Cf[off] = val + res[off];
                    if (MODE == 3) Cb[off] = real ? __float2bfloat16(val) : __float2bfloat16(0.f);
                    if (MODE == 2) {
                        if (real) {
                            const float prev = __bfloat162float(Cb[off]);
                            const float sig  = 1.0f / (1.0f + __expf(-prev));
                            Cb[off] = __float2bfloat16(prev * sig * val);
                        } else {
                            Cb[off] = __float2bfloat16(0.f);
                        }
                    }
                }
            }
        }
    }
}

// ============================= RoPE =============================
__global__ __launch_bounds__(256) void rope_kernel(float* __restrict__ q,
    float* __restrict__ k, const float* __restrict__ cosb,
    const float* __restrict__ sinb, int total)
{
    const int p = blockIdx.x * 256 + threadIdx.x;
    if (p >= total) return;
    const int d  = p % 45;
    int t = p / 45;
    const int h  = t % H_;  t /= H_;
    const int s  = t % S_;
    const int b  = t / S_;

    const size_t base = ((size_t)(b * S_ + s) * D_) + h * DK_;
    const float c1 = cosb[s * DK_ + d],      s1 = sinb[s * DK_ + d];
    const float c2 = cosb[s * DK_ + d + 45], s2 = sinb[s * DK_ + d + 45];

    const float q1 = q[base + d], q2 = q[base + d + 45];
    q[base + d]      = q1 * c1 - q2 * s1;
    q[base + d + 45] = q2 * c2 + q1 * s2;

    const float k1 = k[base + d], k2 = k[base + d + 45];
    k[base + d]      = k1 * c1 - k2 * s1;
    k[base + d + 45] = k2 * c2 + k1 * s2;
}

// ============================= Attention =============================
#define TK 32
__global__ __launch_bounds__(256) void attn_kernel(const float* __restrict__ q,
    const float* __restrict__ k, const float* __restrict__ v,
    bf16* __restrict__ attn)
{
    __shared__ float Ks[TK][96];
    __shared__ float Vs[TK][96];

    const int tid = threadIdx.x;
    const int bx  = blockIdx.x;
    const int bh  = blockIdx.y;
    const int b   = bh / H_;
    const int h   = bh % H_;
    const int t   = tid >> 1;
    const int p   = tid & 1;
    const int qi  = 11 * t + bx;
    const bool active = (qi < S_);
    const float scale = rsqrtf((float)DK_);
    const int wqmax = 11 * ((tid | 63) >> 1) + bx;

    float qreg[48];
    {
        const size_t base = ((size_t)(b * S_ + (active ? qi : 0)) * D_) + h * DK_ + p * 48;
        const int nval = p ? 42 : 48;
        #pragma unroll
        for (int c = 0; c < 24; ++c) {
            float2 val = make_float2(0.f, 0.f);
            if (2 * c < nval) val = *(const float2*)(q + base + 2 * c);
            qreg[2 * c] = val.x; qreg[2 * c + 1] = val.y;
        }
    }
    float o[48];
    #pragma unroll
    for (int d = 0; d < 48; ++d) o[d] = 0.f;
    float m = -1e30f, l = 0.f;

    const int ntiles = (S_ + TK - 1) / TK;
    for (int kt = 0; kt < ntiles; ++kt) {
        __syncthreads();
        for (int idx = tid; idx < TK * 48; idx += 256) {
            const int r = idx / 48, c = idx - (idx / 48) * 48;
            const int krow = kt * TK + r;
            float2 kv = make_float2(0.f, 0.f), vv = make_float2(0.f, 0.f);
            if (krow < S_ && c < 45) {
                const size_t g = ((size_t)(b * S_ + krow) * D_) + h * DK_ + 2 * c;
                kv = *(const float2*)(k + g);
                vv = *(const float2*)(v + g);
            }
            *(float2*)&Ks[r][2 * c] = kv;
            *(float2*)&Vs[r][2 * c] = vv;
        }
        __syncthreads();
        if (kt * TK > wqmax) continue;

        #pragma unroll
        for (int cj = 0; cj < 4; ++cj) {
            float s[8];
            float tmax = m;
            #pragma unroll
            for (int j = 0; j < 8; ++j) {
                const int jj = cj * 8 + j;
                float acc = 0.f;
                const float4* kr = (const float4*)&Ks[jj][48 * p];
                #pragma unroll
                for (int c = 0; c < 12; ++c) {
                    const float4 kv = kr[c];
                    acc += qreg[4*c]   * kv.x + qreg[4*c+1] * kv.y
                         + qreg[4*c+2] * kv.z + qreg[4*c+3] * kv.w;
                }
                acc += __shfl_xor(acc, 1, 64);
                acc *= scale;
                const int kidx = kt * TK + jj;
                s[j] = (active && kidx <= qi) ? acc : -1e30f;
                tmax = fmaxf(tmax, s[j]);
            }
            const float resc = __expf(m - tmax);
            m = tmax;
            l *= resc;
            #pragma unroll
            for (int d = 0; d < 48; ++d) o[d] *= resc;
            #pragma unroll
            for (int j = 0; j < 8; ++j) {
                const float pj = (s[j] > -1e29f) ? __expf(s[j] - m) : 0.f;
                l += pj;
                const int jj = cj * 8 + j;
                const float4* vr = (const float4*)&Vs[jj][48 * p];
                #pragma unroll
                for (int c = 0; c < 12; ++c) {
                    const float4 vv = vr[c];
                    o[4*c]   += pj * vv.x; o[4*c+1] += pj * vv.y;
                    o[4*c+2] += pj * vv.z; o[4*c+3] += pj * vv.w;
                }
            }
        }
    }

    if (active) {
        const float inv = 1.0f / l;
        bf16* op = attn + (size_t)(b * S_ + qi) * KP1 + h * DK_ + p * 48;
        const int nval = p ? 42 : 48;
        for (int c = 0; c < nval; ++c) op[c] = __float2bfloat16(o[c] * inv);
    }
}

// ============================= launch =============================
extern "C" void kernel_launch(void* const* d_in, const int* in_sizes, int n_in,
                              void* d_out, int out_size, void* d_ws, size_t ws_size,
                              hipStream_t stream)
{
    const float* x    = (const float*)d_in[0];
    const float* Wq   = (const float*)d_in[2];
    const float* bq   = (const float*)d_in[3];
    const float* Wk   = (const float*)d_in[4];
    const float* bk   = (const float*)d_in[5];
    const float* Wv   = (const float*)d_in[6];
    const float* bv   = (const float*)d_in[7];
    const float* Wo   = (const float*)d_in[8];
    const float* bo   = (const float*)d_in[9];
    const float* W1   = (const float*)d_in[10];
    const float* b1   = (const float*)d_in[11];
    const float* W2   = (const float*)d_in[12];
    const float* b2   = (const float*)d_in[13];
    const float* W3   = (const float*)d_in[14];
    const float* b3   = (const float*)d_in[15];
    const float* ln1g = (const float*)d_in[16];
    const float* ln1b = (const float*)d_in[17];
    const float* ln2g = (const float*)d_in[18];
    const float* ln2b = (const float*)d_in[19];
    const float* rc   = (const float*)d_in[20];
    const float* rs   = (const float*)d_in[21];
    float* out = (float*)d_out;

    char* wsb = (char*)d_ws;
    size_t off = 0;
    auto nxt = [&](size_t bytes) -> char* {
        char* p = wsb + off; off += (bytes + 255) & ~(size_t)255; return p;
    };
    bf16*  x2  = (bf16*)nxt((size_t)MROWS * KP1 * 2);
    float* qb  = (float*)nxt((size_t)MROWS * D_ * 4);
    float* kb  = (float*)nxt((size_t)MROWS * D_ * 4);   // hb overlays kb..vb
    float* vb  = (float*)nxt((size_t)MROWS * D_ * 4);
    bf16*  ab  = (bf16*)nxt((size_t)MROWS * KP1 * 2);
    bf16*  WqT = (bf16*)nxt((size_t)D_ * KP1 * 2);
    bf16*  WkT = (bf16*)nxt((size_t)D_ * KP1 * 2);
    bf16*  WvT = (bf16*)nxt((size_t)D_ * KP1 * 2);
    bf16*  WoT = (bf16*)nxt((size_t)D_ * KP1 * 2);
    bf16*  W1T = (bf16*)nxt((size_t)FF_ * KP1 * 2);
    bf16*  W3T = (bf16*)nxt((size_t)FF_ * KP1 * 2);
    bf16*  W2T = (bf16*)nxt((size_t)D_ * KP2 * 2);
    float* x1  = qb;          // reuse after attn
    bf16*  hb  = (bf16*)kb;   // M*KP2 bf16 = 67.9MB <= kb+vb (89.9MB)

    const dim3 blk(256);
    const dim3 gD(9, 82);
    const dim3 gF(26, 82);
    const int padN = MROWS * (KP1 - D_);

    // zero bf16 activation pad columns (ws is re-poisoned before every launch)
    zero_pads<<<(padN + 255) / 256, blk, 0, stream>>>(x2);
    zero_pads<<<(padN + 255) / 256, blk, 0, stream>>>(ab);

    // weight casts+transposes (zero-padded K)
    castT<<<dim3(34, 34),  blk, 0, stream>>>(Wq, WqT, D_, D_, KP1);
    castT<<<dim3(34, 34),  blk, 0, stream>>>(Wk, WkT, D_, D_, KP1);
    castT<<<dim3(34, 34),  blk, 0, stream>>>(Wv, WvT, D_, D_, KP1);
    castT<<<dim3(34, 34),  blk, 0, stream>>>(Wo, WoT, D_, D_, KP1);
    castT<<<dim3(34, 102), blk, 0, stream>>>(W1, W1T, D_, FF_, KP1);
    castT<<<dim3(34, 102), blk, 0, stream>>>(W3, W3T, D_, FF_, KP1);
    castT<<<dim3(102, 34), blk, 0, stream>>>(W2, W2T, FF_, D_, KP2);

    // 1) LN1 -> x2 (bf16)
    ln_kernel<<<MROWS, blk, 0, stream>>>(x, ln1g, ln1b, x2);
    // 2) Q/K/V projections (fp32 out)
    gemm_bf16<0><<<gD, blk, 0, stream>>>(x2, WqT, bq, nullptr, qb, nullptr, MROWS, D_, KP1, D_, D_);
    gemm_bf16<0><<<gD, blk, 0, stream>>>(x2, WkT, bk, nullptr, kb, nullptr, MROWS, D_, KP1, D_, D_);
    gemm_bf16<0><<<gD, blk, 0, stream>>>(x2, WvT, bv, nullptr, vb, nullptr, MROWS, D_, KP1, D_, D_);
    // 3) RoPE
    {
        const int total = B_ * S_ * H_ * (DK_ / 2);
        rope_kernel<<<(total + 255) / 256, blk, 0, stream>>>(qb, kb, rc, rs, total);
    }
    // 4) attention -> ab (bf16)
    {
        const dim3 gA(11, B_ * H_);
        attn_kernel<<<gA, blk, 0, stream>>>(qb, kb, vb, ab);
    }
    // 5) O-proj + residual -> x1 (fp32)
    gemm_bf16<1><<<gD, blk, 0, stream>>>(ab, WoT, bo, x, x1, nullptr, MROWS, D_, KP1, D_, D_);
    // 6) LN2 -> x2 (bf16)
    ln_kernel<<<MROWS, blk, 0, stream>>>(x1, ln2g, ln2b, x2);
    // 7) h1 = x2@W1 + b1 (bf16; writes zeros into n-pads up to KP2)
    gemm_bf16<3><<<gF, blk, 0, stream>>>(x2, W1T, b1, nullptr, nullptr, hb, MROWS, FF_, KP1, KP2, KP2);
    // 8) h = silu(h1)*(x2@W3 + b3) (bf16, in place)
    gemm_bf16<2><<<gF, blk, 0, stream>>>(x2, W3T, b3, nullptr, nullptr, hb, MROWS, FF_, KP1, KP2, KP2);
    // 9) out = x1 + h@W2 + b2 (fp32)
    gemm_bf16<1><<<gD, blk, 0, stream>>>(hb, W2T, b2, x1, out, nullptr, MROWS, D_, KP2, D_, D_);
}

// Round 6
// 1234.579 us; speedup vs baseline: 6.4777x; 2.6800x over previous
//
#include <hip/hip_runtime.h>
#include <hip/hip_bf16.h>
#include <cstdint>
#include <cstddef>

#define B_  8
#define S_  1300
#define D_  1080
#define H_  12
#define DK_ 90
#define FF_ 3240
#define MROWS (B_*S_)   // 10400
#define KP1 1088        // 1080 padded to /32
#define KP2 3264        // 3240 padded to /32
#define SP  1312        // S padded to /32 (41 K-tiles)
#define QSCALE 0.105409255338946f   // 1/sqrt(90)

typedef __hip_bfloat16 bf16;
typedef __bf16 bf16x8 __attribute__((ext_vector_type(8)));
typedef float  f32x4  __attribute__((ext_vector_type(4)));
typedef unsigned short u16x8 __attribute__((ext_vector_type(8)));

__device__ __forceinline__ void gload16(const void* g, void* l) {
    __builtin_amdgcn_global_load_lds((const __attribute__((address_space(1))) void*)g,
                                     (__attribute__((address_space(3))) void*)l, 16, 0, 0);
}
__device__ __forceinline__ unsigned short bf16bits(float f) {
    bf16 b = __float2bfloat16(f);
    return *(unsigned short*)&b;
}

// ================== zero pad columns [D_, KP1) of bf16 [MROWS, KP1] ==================
__global__ __launch_bounds__(256) void zero_pads(bf16* __restrict__ buf)
{
    const int idx = blockIdx.x * 256 + threadIdx.x;
    if (idx >= MROWS * (KP1 - D_)) return;
    const int row = idx >> 3, col = D_ + (idx & 7);
    buf[(size_t)row * KP1 + col] = __float2bfloat16(0.f);
}

// ===================== weight cast + transpose =====================
__global__ __launch_bounds__(256) void castT(const float* __restrict__ W,
    bf16* __restrict__ WT, int K, int N, int KP)
{
    __shared__ unsigned short t[32][33];
    const int tx = threadIdx.x & 31, ty = threadIdx.x >> 5;
    const int k0 = blockIdx.x * 32, n0 = blockIdx.y * 32;
    #pragma unroll
    for (int i = 0; i < 4; ++i) {
        const int k = k0 + ty + 8 * i;
        const int n = n0 + tx;
        float v = (k < K && n < N) ? W[(size_t)k * N + n] : 0.f;
        t[ty + 8 * i][tx] = bf16bits(v);
    }
    __syncthreads();
    #pragma unroll
    for (int i = 0; i < 4; ++i) {
        const int n = n0 + ty + 8 * i;
        const int kk = k0 + tx;
        if (n < N && kk < KP) *(unsigned short*)&WT[(size_t)n * KP + kk] = t[tx][ty + 8 * i];
    }
}

// ============================= LayerNorm =============================
__global__ __launch_bounds__(256) void ln_kernel(const float* __restrict__ x,
    const float* __restrict__ g, const float* __restrict__ b,
    bf16* __restrict__ y)
{
    __shared__ float xs[D_];
    __shared__ float red[8];
    const int row = blockIdx.x;
    const int tid = threadIdx.x;
    const float* xr = x + (size_t)row * D_;

    float s = 0.f, sq = 0.f;
    for (int d = tid; d < D_; d += 256) {
        float v = xr[d];
        xs[d] = v;
        s += v; sq += v * v;
    }
    #pragma unroll
    for (int off = 32; off > 0; off >>= 1) {
        s  += __shfl_down(s,  off, 64);
        sq += __shfl_down(sq, off, 64);
    }
    const int wave = tid >> 6, lane = tid & 63;
    if (lane == 0) { red[wave] = s; red[4 + wave] = sq; }
    __syncthreads();
    if (tid == 0) {
        float ts = 0.f, tq = 0.f;
        #pragma unroll
        for (int w = 0; w < 4; ++w) { ts += red[w]; tq += red[4 + w]; }
        red[0] = ts; red[4] = tq;
    }
    __syncthreads();
    const float mean = red[0] * (1.0f / D_);
    const float var  = red[4] * (1.0f / D_) - mean * mean;
    const float rstd = rsqrtf(var + 1e-5f);
    bf16* yr = y + (size_t)row * KP1;
    for (int d = tid; d < D_; d += 256)
        yr[d] = __float2bfloat16((xs[d] - mean) * rstd * g[d] + b[d]);
}

// ============================= bf16 MFMA GEMM =============================
template<int MODE>
__global__ __launch_bounds__(256) void gemm_bf16(
    const bf16* __restrict__ A, const bf16* __restrict__ BT,
    const float* __restrict__ bias, const float* __restrict__ res,
    float* __restrict__ Cf, bf16* __restrict__ Cb,
    int M, int N, int KP, int LDC, int NP)
{
    __shared__ unsigned short As[128 * 32];
    __shared__ unsigned short Bs[128 * 32];

    const int tid = threadIdx.x;
    const int w = tid >> 6, l = tid & 63;
    const int m0 = blockIdx.y * 128, n0 = blockIdx.x * 128;

    const int rs = w * 16 + (l >> 2);
    const int kc = (l & 3) * 8;
    const int ar0 = min(m0 + rs,      M - 1);
    const int ar1 = min(m0 + rs + 64, M - 1);
    const int br0 = min(n0 + rs,      N - 1);
    const int br1 = min(n0 + rs + 64, N - 1);

    const int wm = (w >> 1) * 64, wn = (w & 1) * 64;
    const int lr = l & 15, kq = l >> 4;

    const unsigned short* aptr[4];
    const unsigned short* bptr[4];
    #pragma unroll
    for (int i = 0; i < 4; ++i) {
        aptr[i] = &As[(wm + i * 16 + lr) * 32 + kq * 8];
        bptr[i] = &Bs[(wn + i * 16 + lr) * 32 + kq * 8];
    }

    f32x4 acc[4][4] = {};

    const int nkt = KP >> 5;
    for (int kt = 0; kt < nkt; ++kt) {
        const int k0 = kt << 5;
        __syncthreads();
        gload16(A  + (size_t)ar0 * KP + k0 + kc, &As[w * 512]);
        gload16(A  + (size_t)ar1 * KP + k0 + kc, &As[2048 + w * 512]);
        gload16(BT + (size_t)br0 * KP + k0 + kc, &Bs[w * 512]);
        gload16(BT + (size_t)br1 * KP + k0 + kc, &Bs[2048 + w * 512]);
        __syncthreads();

        bf16x8 af[4], bv[4];
        #pragma unroll
        for (int i = 0; i < 4; ++i) af[i] = *(const bf16x8*)aptr[i];
        #pragma unroll
        for (int j = 0; j < 4; ++j) bv[j] = *(const bf16x8*)bptr[j];
        #pragma unroll
        for (int i = 0; i < 4; ++i)
            #pragma unroll
            for (int j = 0; j < 4; ++j)
                acc[i][j] = __builtin_amdgcn_mfma_f32_16x16x32_bf16(af[i], bv[j], acc[i][j], 0, 0, 0);
    }

    #pragma unroll
    for (int j = 0; j < 4; ++j) {
        const int n = n0 + wn + j * 16 + lr;
        if (n >= NP) continue;
        const bool real = (n < N);
        const float bn = real ? bias[n] : 0.f;
        #pragma unroll
        for (int i = 0; i < 4; ++i) {
            const int rowb = m0 + wm + i * 16 + kq * 4;
            #pragma unroll
            for (int r = 0; r < 4; ++r) {
                const int m = rowb + r;
                if (m < M) {
                    const size_t off = (size_t)m * LDC + n;
                    float val = acc[i][j][r] + bn;
                    if (MODE == 0) Cf[off] = val;
                    if (MODE == 1) Cf[off] = val + res[off];
                    if (MODE == 3) Cb[off] = real ? __float2bfloat16(val) : __float2bfloat16(0.f);
                    if (MODE == 2) {
                        if (real) {
                            const float prev = __bfloat162float(Cb[off]);
                            const float sig  = 1.0f / (1.0f + __expf(-prev));
                            Cb[off] = __float2bfloat16(prev * sig * val);
                        } else {
                            Cb[off] = __float2bfloat16(0.f);
                        }
                    }
                }
            }
        }
    }
}

// ============================= RoPE + head layout (fp32 -> bf16) =============================
// qb/kb fp32 [B,S,D] -> Qa/Ka bf16 [B*H][SP][96]; Q scaled by 1/sqrt(DK).
__global__ __launch_bounds__(256) void rope_qk(const float* __restrict__ qb,
    const float* __restrict__ kb, const float* __restrict__ cosb,
    const float* __restrict__ sinb, bf16* __restrict__ Qa, bf16* __restrict__ Ka)
{
    const int s = blockIdx.x;       // 0..SP-1
    const int b = blockIdx.y;
    const int tid = threadIdx.x;

    if (s >= S_) {
        for (int idx = tid; idx < H_ * 96; idx += 256) {
            const int h = idx / 96, c = idx - (idx / 96) * 96;
            const size_t o = ((size_t)(b * H_ + h) * SP + s) * 96 + c;
            Qa[o] = __float2bfloat16(0.f);
            Ka[o] = __float2bfloat16(0.f);
        }
        return;
    }

    const float* qr = qb + (size_t)(b * S_ + s) * D_;
    const float* kr = kb + (size_t)(b * S_ + s) * D_;

    for (int idx = tid; idx < H_ * 45; idx += 256) {
        const int h = idx / 45, d = idx - (idx / 45) * 45;
        const float c1 = cosb[s * DK_ + d],      s1 = sinb[s * DK_ + d];
        const float c2 = cosb[s * DK_ + d + 45], s2 = sinb[s * DK_ + d + 45];
        const size_t o = ((size_t)(b * H_ + h) * SP + s) * 96;
        const float q1 = qr[h * DK_ + d], q2 = qr[h * DK_ + d + 45];
        Qa[o + d]      = __float2bfloat16((q1 * c1 - q2 * s1) * QSCALE);
        Qa[o + d + 45] = __float2bfloat16((q2 * c2 + q1 * s2) * QSCALE);
        const float k1 = kr[h * DK_ + d], k2 = kr[h * DK_ + d + 45];
        Ka[o + d]      = __float2bfloat16(k1 * c1 - k2 * s1);
        Ka[o + d + 45] = __float2bfloat16(k2 * c2 + k1 * s2);
    }
    for (int idx = tid; idx < H_ * 6; idx += 256) {
        const int h = idx / 6, c = 90 + (idx - (idx / 6) * 6);
        const size_t o = ((size_t)(b * H_ + h) * SP + s) * 96 + c;
        Qa[o] = __float2bfloat16(0.f);
        Ka[o] = __float2bfloat16(0.f);
    }
}

// ============================= V transpose (fp32 -> bf16) =============================
// vb fp32 [B,S,D] -> Vt bf16 [B*H][96][SP]
__global__ __launch_bounds__(256) void vtrans(const float* __restrict__ vb,
    bf16* __restrict__ Vt)
{
    __shared__ float T[96][33];
    const int k0 = blockIdx.x * 32;
    const int bh = blockIdx.y;
    const int b = bh / H_, h = bh % H_;
    const int tid = threadIdx.x;

    for (int idx = tid; idx < 32 * 90; idx += 256) {
        const int r = idx / 90, d = idx - (idx / 90) * 90;
        const int s = k0 + r;
        T[d][r] = (s < S_) ? vb[(size_t)(b * S_ + s) * D_ + h * DK_ + d] : 0.f;
    }
    for (int idx = tid; idx < 32 * 6; idx += 256) {
        const int r = idx / 6, d = 90 + (idx - (idx / 6) * 6);
        T[d][r] = 0.f;
    }
    __syncthreads();
    for (int idx = tid; idx < 96 * 4; idx += 256) {
        const int d = idx >> 2, kk = (idx & 3) * 8;
        u16x8 v;
        #pragma unroll
        for (int i = 0; i < 8; ++i) v[i] = bf16bits(T[d][kk + i]);
        *(u16x8*)(Vt + ((size_t)bh * 96 + d) * SP + k0 + kk) = v;
    }
}

// ============================= MFMA flash attention =============================
// grid (21, B*H), 256 thr = 4 waves. Block = 64 queries (wave w: 16), K/V tiles = 32.
__global__ __launch_bounds__(256) void attn_mfma(const bf16* __restrict__ Qa,
    const bf16* __restrict__ Ka, const bf16* __restrict__ Vt,
    bf16* __restrict__ ab)
{
    __shared__ unsigned short Qs[64][104];   // 13312 B
    __shared__ unsigned short Ks[32][104];   //  6656 B
    __shared__ unsigned short Vs[96][40];    //  7680 B
    __shared__ unsigned short Ps[4][16][40]; //  5120 B

    const int tid = threadIdx.x;
    const int w = tid >> 6, l = tid & 63;
    const int lr = l & 15, kq = l >> 4;
    const int qblk = (int)gridDim.x - 1 - (int)blockIdx.x;   // big blocks first
    const int q0 = qblk * 64;
    const int bh = blockIdx.y;
    const int b = bh / H_, h = bh % H_;

    const bf16* Qg = Qa + (size_t)bh * SP * 96;
    const bf16* Kg = Ka + (size_t)bh * SP * 96;
    const bf16* Vg = Vt + (size_t)bh * 96 * SP;

    // ---- stage Q (64 rows x 96 cols) ----
    for (int c = tid; c < 768; c += 256) {
        const int row = c / 12, cc = c - row * 12;
        const int rg = q0 + row;
        u16x8 v = (u16x8)0;
        if (rg < SP) v = *(const u16x8*)(Qg + (size_t)rg * 96 + cc * 8);
        *(u16x8*)&Qs[row][cc * 8] = v;
    }
    __syncthreads();

    bf16x8 Qf[3];
    #pragma unroll
    for (int kf = 0; kf < 3; ++kf)
        Qf[kf] = *(const bf16x8*)&Qs[w * 16 + lr][kf * 32 + kq * 8];

    const int qw0 = q0 + w * 16;
    const int wlq = (qw0 < S_) ? min(qw0 + 15, S_ - 1) : -1;
    const int lastq = min(q0 + 63, S_ - 1);
    const int ntiles = lastq / 32 + 1;

    f32x4 Of[6] = {};
    float mrun[4] = {-1e30f, -1e30f, -1e30f, -1e30f};
    float lrun[4] = {0.f, 0.f, 0.f, 0.f};

    for (int kt = 0; kt < ntiles; ++kt) {
        const int k0 = kt * 32;
        __syncthreads();
        // stage K tile (32 rows x 96 cols = 384 chunks of 8)
        for (int c = tid; c < 384; c += 256) {
            const int row = c / 12, cc = c - (c / 12) * 12;
            *(u16x8*)&Ks[row][cc * 8] = *(const u16x8*)(Kg + (size_t)(k0 + row) * 96 + cc * 8);
        }
        // stage V tile (96 dims x 32 keys = 384 chunks of 8)
        for (int c = tid; c < 384; c += 256) {
            const int d = c >> 2, kk = (c & 3) * 8;
            *(u16x8*)&Vs[d][kk] = *(const u16x8*)(Vg + (size_t)d * SP + k0 + kk);
        }
        __syncthreads();

        if (k0 > wlq) continue;   // wave-uniform skip; barriers above still executed

        // ---- S = Q K^T ----
        f32x4 sg0 = {0.f, 0.f, 0.f, 0.f}, sg1 = {0.f, 0.f, 0.f, 0.f};
        #pragma unroll
        for (int kf = 0; kf < 3; ++kf) {
            bf16x8 k0f = *(const bf16x8*)&Ks[lr][kf * 32 + kq * 8];
            bf16x8 k1f = *(const bf16x8*)&Ks[16 + lr][kf * 32 + kq * 8];
            sg0 = __builtin_amdgcn_mfma_f32_16x16x32_bf16(Qf[kf], k0f, sg0, 0, 0, 0);
            sg1 = __builtin_amdgcn_mfma_f32_16x16x32_bf16(Qf[kf], k1f, sg1, 0, 0, 0);
        }

        // ---- online softmax (C-layout: row=4*kq+r -> query, col=lr -> key) ----
        const int key0 = k0 + lr, key1 = k0 + 16 + lr;
        float s0[4], s1[4], m4[4];
        #pragma unroll
        for (int r = 0; r < 4; ++r) {
            const int qrow = qw0 + 4 * kq + r;
            s0[r] = (key0 <= qrow && key0 < S_) ? sg0[r] : -1e30f;
            s1[r] = (key1 <= qrow && key1 < S_) ? sg1[r] : -1e30f;
            m4[r] = fmaxf(s0[r], s1[r]);
        }
        #pragma unroll
        for (int st = 1; st < 16; st <<= 1)
            #pragma unroll
            for (int r = 0; r < 4; ++r)
                m4[r] = fmaxf(m4[r], __shfl_xor(m4[r], st, 64));
        float resc[4], ls[4];
        #pragma unroll
        for (int r = 0; r < 4; ++r) {
            const float nm = fmaxf(mrun[r], m4[r]);
            resc[r] = __expf(mrun[r] - nm);
            mrun[r] = nm;
            const float e0 = (s0[r] > -1e29f) ? __expf(s0[r] - nm) : 0.f;
            const float e1 = (s1[r] > -1e29f) ? __expf(s1[r] - nm) : 0.f;
            Ps[w][4 * kq + r][lr]      = bf16bits(e0);
            Ps[w][4 * kq + r][16 + lr] = bf16bits(e1);
            ls[r] = e0 + e1;
        }
        #pragma unroll
        for (int st = 1; st < 16; st <<= 1)
            #pragma unroll
            for (int r = 0; r < 4; ++r)
                ls[r] += __shfl_xor(ls[r], st, 64);
        #pragma unroll
        for (int r = 0; r < 4; ++r) lrun[r] = lrun[r] * resc[r] + ls[r];
        #pragma unroll
        for (int c = 0; c < 6; ++c)
            #pragma unroll
            for (int r = 0; r < 4; ++r)
                Of[c][r] *= resc[r];

        // ---- O += P V  (P via LDS round-trip; same-wave, no barrier needed) ----
        bf16x8 Pf = *(const bf16x8*)&Ps[w][lr][kq * 8];
        #pragma unroll
        for (int c = 0; c < 6; ++c) {
            bf16x8 Vf = *(const bf16x8*)&Vs[16 * c + lr][kq * 8];
            Of[c] = __builtin_amdgcn_mfma_f32_16x16x32_bf16(Pf, Vf, Of[c], 0, 0, 0);
        }
    }

    // ---- epilogue ----
    float inv[4];
    #pragma unroll
    for (int r = 0; r < 4; ++r) inv[r] = 1.0f / lrun[r];
    #pragma unroll
    for (int c = 0; c < 6; ++c) {
        const int dim = 16 * c + lr;
        if (dim >= DK_) continue;
        #pragma unroll
        for (int r = 0; r < 4; ++r) {
            const int qrow = qw0 + 4 * kq + r;
            if (qrow < S_)
                ab[(size_t)(b * S_ + qrow) * KP1 + h * DK_ + dim] =
                    __float2bfloat16(Of[c][r] * inv[r]);
        }
    }
}

// ============================= launch =============================
extern "C" void kernel_launch(void* const* d_in, const int* in_sizes, int n_in,
                              void* d_out, int out_size, void* d_ws, size_t ws_size,
                              hipStream_t stream)
{
    const float* x    = (const float*)d_in[0];
    const float* Wq   = (const float*)d_in[2];
    const float* bq   = (const float*)d_in[3];
    const float* Wk   = (const float*)d_in[4];
    const float* bk   = (const float*)d_in[5];
    const float* Wv   = (const float*)d_in[6];
    const float* bv   = (const float*)d_in[7];
    const float* Wo   = (const float*)d_in[8];
    const float* bo   = (const float*)d_in[9];
    const float* W1   = (const float*)d_in[10];
    const float* b1   = (const float*)d_in[11];
    const float* W2   = (const float*)d_in[12];
    const float* b2   = (const float*)d_in[13];
    const float* W3   = (const float*)d_in[14];
    const float* b3   = (const float*)d_in[15];
    const float* ln1g = (const float*)d_in[16];
    const float* ln1b = (const float*)d_in[17];
    const float* ln2g = (const float*)d_in[18];
    const float* ln2b = (const float*)d_in[19];
    const float* rc   = (const float*)d_in[20];
    const float* rs   = (const float*)d_in[21];
    float* out = (float*)d_out;

    char* wsb = (char*)d_ws;
    size_t off = 0;
    auto nxt = [&](size_t bytes) -> char* {
        char* p = wsb + off; off += (bytes + 255) & ~(size_t)255; return p;
    };
    bf16*  x2  = (bf16*)nxt((size_t)MROWS * KP1 * 2);
    float* qb  = (float*)nxt((size_t)MROWS * D_ * 4);
    float* kb  = (float*)nxt((size_t)MROWS * D_ * 4);   // later: Vt, then hb
    float* vb  = (float*)nxt((size_t)MROWS * D_ * 4);
    bf16*  ab  = (bf16*)nxt((size_t)MROWS * KP1 * 2);
    bf16*  WqT = (bf16*)nxt((size_t)D_ * KP1 * 2);
    bf16*  WkT = (bf16*)nxt((size_t)D_ * KP1 * 2);
    bf16*  WvT = (bf16*)nxt((size_t)D_ * KP1 * 2);
    bf16*  WoT = (bf16*)nxt((size_t)D_ * KP1 * 2);
    bf16*  W1T = (bf16*)nxt((size_t)FF_ * KP1 * 2);
    bf16*  W3T = (bf16*)nxt((size_t)FF_ * KP1 * 2);
    bf16*  W2T = (bf16*)nxt((size_t)D_ * KP2 * 2);
    bf16*  Qa  = (bf16*)nxt((size_t)B_ * H_ * SP * 96 * 2);
    bf16*  Ka  = (bf16*)nxt((size_t)B_ * H_ * SP * 96 * 2);
    float* x1  = qb;          // reuse after rope
    bf16*  Vt  = (bf16*)kb;   // kb dead after rope_qk
    bf16*  hb  = (bf16*)kb;   // M*KP2 bf16 <= kb+vb (dead after attn)

    const dim3 blk(256);
    const dim3 gD(9, 82);
    const dim3 gF(26, 82);
    const int padN = MROWS * (KP1 - D_);

    zero_pads<<<(padN + 255) / 256, blk, 0, stream>>>(x2);
    zero_pads<<<(padN + 255) / 256, blk, 0, stream>>>(ab);

    castT<<<dim3(34, 34),  blk, 0, stream>>>(Wq, WqT, D_, D_, KP1);
    castT<<<dim3(34, 34),  blk, 0, stream>>>(Wk, WkT, D_, D_, KP1);
    castT<<<dim3(34, 34),  blk, 0, stream>>>(Wv, WvT, D_, D_, KP1);
    castT<<<dim3(34, 34),  blk, 0, stream>>>(Wo, WoT, D_, D_, KP1);
    castT<<<dim3(34, 102), blk, 0, stream>>>(W1, W1T, D_, FF_, KP1);
    castT<<<dim3(34, 102), blk, 0, stream>>>(W3, W3T, D_, FF_, KP1);
    castT<<<dim3(102, 34), blk, 0, stream>>>(W2, W2T, FF_, D_, KP2);

    // 1) LN1
    ln_kernel<<<MROWS, blk, 0, stream>>>(x, ln1g, ln1b, x2);
    // 2) Q/K/V projections (fp32)
    gemm_bf16<0><<<gD, blk, 0, stream>>>(x2, WqT, bq, nullptr, qb, nullptr, MROWS, D_, KP1, D_, D_);
    gemm_bf16<0><<<gD, blk, 0, stream>>>(x2, WkT, bk, nullptr, kb, nullptr, MROWS, D_, KP1, D_, D_);
    gemm_bf16<0><<<gD, blk, 0, stream>>>(x2, WvT, bv, nullptr, vb, nullptr, MROWS, D_, KP1, D_, D_);
    // 3) RoPE + head layout (kb dead after this)
    rope_qk<<<dim3(SP, B_), blk, 0, stream>>>(qb, kb, rc, rs, Qa, Ka);
    // 4) V transpose into kb region (vb dead after this)
    vtrans<<<dim3(41, B_ * H_), blk, 0, stream>>>(vb, Vt);
    // 5) MFMA flash attention -> ab
    attn_mfma<<<dim3(21, B_ * H_), blk, 0, stream>>>(Qa, Ka, Vt, ab);
    // 6) O-proj + residual -> x1
    gemm_bf16<1><<<gD, blk, 0, stream>>>(ab, WoT, bo, x, x1, nullptr, MROWS, D_, KP1, D_, D_);
    // 7) LN2
    ln_kernel<<<MROWS, blk, 0, stream>>>(x1, ln2g, ln2b, x2);
    // 8) h1 = x2@W1 + b1
    gemm_bf16<3><<<gF, blk, 0, stream>>>(x2, W1T, b1, nullptr, nullptr, hb, MROWS, FF_, KP1, KP2, KP2);
    // 9) h = silu(h1)*(x2@W3 + b3)
    gemm_bf16<2><<<gF, blk, 0, stream>>>(x2, W3T, b3, nullptr, nullptr, hb, MROWS, FF_, KP1, KP2, KP2);
    // 10) out = x1 + h@W2 + b2
    gemm_bf16<1><<<gD, blk, 0, stream>>>(hb, W2T, b2, x1, out, nullptr, MROWS, D_, KP2, D_, D_);
}

// Round 7
// 1147.231 us; speedup vs baseline: 6.9709x; 1.0761x over previous
//
#include <hip/hip_runtime.h>
#include <hip/hip_bf16.h>
#include <cstdint>
#include <cstddef>

#define B_  8
#define S_  1300
#define D_  1080
#define H_  12
#define DK_ 90
#define FF_ 3240
#define MROWS (B_*S_)   // 10400
#define KP1 1088        // 1080 padded to /32
#define KP2 3264        // 3240 padded to /32
#define SP  1312        // S padded to /32 (41 K-tiles)
#define QKVN 3240       // 3*D
#define QSCALE 0.105409255338946f   // 1/sqrt(90)

typedef __hip_bfloat16 bf16;
typedef __bf16 bf16x8 __attribute__((ext_vector_type(8)));
typedef float  f32x4  __attribute__((ext_vector_type(4)));
typedef unsigned short u16x8 __attribute__((ext_vector_type(8)));

__device__ __forceinline__ void gload16(const void* g, void* l) {
    __builtin_amdgcn_global_load_lds((const __attribute__((address_space(1))) void*)g,
                                     (__attribute__((address_space(3))) void*)l, 16, 0, 0);
}
__device__ __forceinline__ unsigned short bf16bits(float f) {
    bf16 b = __float2bfloat16(f);
    return *(unsigned short*)&b;
}

// ================== zero pad columns [D_, KP1) of bf16 [MROWS, KP1] ==================
__global__ __launch_bounds__(256) void zero_pads(bf16* __restrict__ buf)
{
    const int idx = blockIdx.x * 256 + threadIdx.x;
    if (idx >= MROWS * (KP1 - D_)) return;
    const int row = idx >> 3, col = D_ + (idx & 7);
    buf[(size_t)row * KP1 + col] = __float2bfloat16(0.f);
}

// ================== concat qkv bias ==================
__global__ __launch_bounds__(256) void bcat(const float* __restrict__ bq,
    const float* __restrict__ bk, const float* __restrict__ bv,
    float* __restrict__ bqkv)
{
    const int i = blockIdx.x * 256 + threadIdx.x;
    if (i >= QKVN) return;
    bqkv[i] = (i < D_) ? bq[i] : (i < 2 * D_) ? bk[i - D_] : bv[i - 2 * D_];
}

// ===================== weight cast + transpose =====================
__global__ __launch_bounds__(256) void castT(const float* __restrict__ W,
    bf16* __restrict__ WT, int K, int N, int KP)
{
    __shared__ unsigned short t[32][33];
    const int tx = threadIdx.x & 31, ty = threadIdx.x >> 5;
    const int k0 = blockIdx.x * 32, n0 = blockIdx.y * 32;
    #pragma unroll
    for (int i = 0; i < 4; ++i) {
        const int k = k0 + ty + 8 * i;
        const int n = n0 + tx;
        float v = (k < K && n < N) ? W[(size_t)k * N + n] : 0.f;
        t[ty + 8 * i][tx] = bf16bits(v);
    }
    __syncthreads();
    #pragma unroll
    for (int i = 0; i < 4; ++i) {
        const int n = n0 + ty + 8 * i;
        const int kk = k0 + tx;
        if (n < N && kk < KP) *(unsigned short*)&WT[(size_t)n * KP + kk] = t[tx][ty + 8 * i];
    }
}

// ============================= LayerNorm =============================
__global__ __launch_bounds__(256) void ln_kernel(const float* __restrict__ x,
    const float* __restrict__ g, const float* __restrict__ b,
    bf16* __restrict__ y)
{
    __shared__ float xs[D_];
    __shared__ float red[8];
    const int row = blockIdx.x;
    const int tid = threadIdx.x;
    const float* xr = x + (size_t)row * D_;

    float s = 0.f, sq = 0.f;
    for (int d = tid; d < D_; d += 256) {
        float v = xr[d];
        xs[d] = v;
        s += v; sq += v * v;
    }
    #pragma unroll
    for (int off = 32; off > 0; off >>= 1) {
        s  += __shfl_down(s,  off, 64);
        sq += __shfl_down(sq, off, 64);
    }
    const int wave = tid >> 6, lane = tid & 63;
    if (lane == 0) { red[wave] = s; red[4 + wave] = sq; }
    __syncthreads();
    if (tid == 0) {
        float ts = 0.f, tq = 0.f;
        #pragma unroll
        for (int w = 0; w < 4; ++w) { ts += red[w]; tq += red[4 + w]; }
        red[0] = ts; red[4] = tq;
    }
    __syncthreads();
    const float mean = red[0] * (1.0f / D_);
    const float var  = red[4] * (1.0f / D_) - mean * mean;
    const float rstd = rsqrtf(var + 1e-5f);
    bf16* yr = y + (size_t)row * KP1;
    for (int d = tid; d < D_; d += 256)
        yr[d] = __float2bfloat16((xs[d] - mean) * rstd * g[d] + b[d]);
}

// ============================= bf16 MFMA GEMM =============================
template<int MODE>
__global__ __launch_bounds__(256) void gemm_bf16(
    const bf16* __restrict__ A, const bf16* __restrict__ BT,
    const float* __restrict__ bias, const float* __restrict__ res,
    float* __restrict__ Cf, bf16* __restrict__ Cb,
    int M, int N, int KP, int LDC, int NP)
{
    __shared__ unsigned short As[128 * 32];
    __shared__ unsigned short Bs[128 * 32];

    const int tid = threadIdx.x;
    const int w = tid >> 6, l = tid & 63;
    const int m0 = blockIdx.y * 128, n0 = blockIdx.x * 128;

    const int rs = w * 16 + (l >> 2);
    const int kc = (l & 3) * 8;
    const int ar0 = min(m0 + rs,      M - 1);
    const int ar1 = min(m0 + rs + 64, M - 1);
    const int br0 = min(n0 + rs,      N - 1);
    const int br1 = min(n0 + rs + 64, N - 1);

    const int wm = (w >> 1) * 64, wn = (w & 1) * 64;
    const int lr = l & 15, kq = l >> 4;

    const unsigned short* aptr[4];
    const unsigned short* bptr[4];
    #pragma unroll
    for (int i = 0; i < 4; ++i) {
        aptr[i] = &As[(wm + i * 16 + lr) * 32 + kq * 8];
        bptr[i] = &Bs[(wn + i * 16 + lr) * 32 + kq * 8];
    }

    f32x4 acc[4][4] = {};

    const int nkt = KP >> 5;
    for (int kt = 0; kt < nkt; ++kt) {
        const int k0 = kt << 5;
        __syncthreads();
        gload16(A  + (size_t)ar0 * KP + k0 + kc, &As[w * 512]);
        gload16(A  + (size_t)ar1 * KP + k0 + kc, &As[2048 + w * 512]);
        gload16(BT + (size_t)br0 * KP + k0 + kc, &Bs[w * 512]);
        gload16(BT + (size_t)br1 * KP + k0 + kc, &Bs[2048 + w * 512]);
        __syncthreads();

        bf16x8 af[4], bv[4];
        #pragma unroll
        for (int i = 0; i < 4; ++i) af[i] = *(const bf16x8*)aptr[i];
        #pragma unroll
        for (int j = 0; j < 4; ++j) bv[j] = *(const bf16x8*)bptr[j];
        #pragma unroll
        for (int i = 0; i < 4; ++i)
            #pragma unroll
            for (int j = 0; j < 4; ++j)
                acc[i][j] = __builtin_amdgcn_mfma_f32_16x16x32_bf16(af[i], bv[j], acc[i][j], 0, 0, 0);
    }

    #pragma unroll
    for (int j = 0; j < 4; ++j) {
        const int n = n0 + wn + j * 16 + lr;
        if (n >= NP) continue;
        const bool real = (n < N);
        const float bn = real ? bias[n] : 0.f;
        #pragma unroll
        for (int i = 0; i < 4; ++i) {
            const int rowb = m0 + wm + i * 16 + kq * 4;
            #pragma unroll
            for (int r = 0; r < 4; ++r) {
                const int m = rowb + r;
                if (m < M) {
                    const size_t off = (size_t)m * LDC + n;
                    float val = acc[i][j][r] + bn;
                    if (MODE == 0) Cf[off] = val;
                    if (MODE == 1) Cf[off] = val + res[off];
                    if (MODE == 3) Cb[off] = real ? __float2bfloat16(val) : __float2bfloat16(0.f);
                    if (MODE == 2) {
                        if (real) {
                            const float prev = __bfloat162float(Cb[off]);
                            const float sig  = 1.0f / (1.0f + __expf(-prev));
                            Cb[off] = __float2bfloat16(prev * sig * val);
                        } else {
                            Cb[off] = __float2bfloat16(0.f);
                        }
                    }
                }
            }
        }
    }
}

// ============================= RoPE + head layout (bf16 qkv -> bf16 Qa/Ka) =============================
__global__ __launch_bounds__(256) void rope_qk(const bf16* __restrict__ qkv,
    const float* __restrict__ cosb, const float* __restrict__ sinb,
    bf16* __restrict__ Qa, bf16* __restrict__ Ka)
{
    const int s = blockIdx.x;       // 0..SP-1
    const int b = blockIdx.y;
    const int tid = threadIdx.x;

    if (s >= S_) {
        for (int idx = tid; idx < H_ * 96; idx += 256) {
            const int h = idx / 96, c = idx - (idx / 96) * 96;
            const size_t o = ((size_t)(b * H_ + h) * SP + s) * 96 + c;
            Qa[o] = __float2bfloat16(0.f);
            Ka[o] = __float2bfloat16(0.f);
        }
        return;
    }

    const bf16* row = qkv + (size_t)(b * S_ + s) * QKVN;

    for (int idx = tid; idx < H_ * 45; idx += 256) {
        const int h = idx / 45, d = idx - (idx / 45) * 45;
        const float c1 = cosb[s * DK_ + d],      s1 = sinb[s * DK_ + d];
        const float c2 = cosb[s * DK_ + d + 45], s2 = sinb[s * DK_ + d + 45];
        const size_t o = ((size_t)(b * H_ + h) * SP + s) * 96;
        const float q1 = __bfloat162float(row[h * DK_ + d]);
        const float q2 = __bfloat162float(row[h * DK_ + d + 45]);
        Qa[o + d]      = __float2bfloat16((q1 * c1 - q2 * s1) * QSCALE);
        Qa[o + d + 45] = __float2bfloat16((q2 * c2 + q1 * s2) * QSCALE);
        const float k1 = __bfloat162float(row[D_ + h * DK_ + d]);
        const float k2 = __bfloat162float(row[D_ + h * DK_ + d + 45]);
        Ka[o + d]      = __float2bfloat16(k1 * c1 - k2 * s1);
        Ka[o + d + 45] = __float2bfloat16(k2 * c2 + k1 * s2);
    }
    for (int idx = tid; idx < H_ * 6; idx += 256) {
        const int h = idx / 6, c = 90 + (idx - (idx / 6) * 6);
        const size_t o = ((size_t)(b * H_ + h) * SP + s) * 96 + c;
        Qa[o] = __float2bfloat16(0.f);
        Ka[o] = __float2bfloat16(0.f);
    }
}

// ============================= V transpose (bf16 qkv -> bf16 Vt) =============================
// v section of qkv -> Vt bf16 [B*H][96][SP]
__global__ __launch_bounds__(256) void vtrans(const bf16* __restrict__ qkv,
    bf16* __restrict__ Vt)
{
    __shared__ float T[96][33];
    const int k0 = blockIdx.x * 32;
    const int bh = blockIdx.y;
    const int b = bh / H_, h = bh % H_;
    const int tid = threadIdx.x;

    for (int idx = tid; idx < 32 * 90; idx += 256) {
        const int r = idx / 90, d = idx - (idx / 90) * 90;
        const int s = k0 + r;
        T[d][r] = (s < S_) ?
            __bfloat162float(qkv[(size_t)(b * S_ + s) * QKVN + 2 * D_ + h * DK_ + d]) : 0.f;
    }
    for (int idx = tid; idx < 32 * 6; idx += 256) {
        const int r = idx / 6, d = 90 + (idx - (idx / 6) * 6);
        T[d][r] = 0.f;
    }
    __syncthreads();
    for (int idx = tid; idx < 96 * 4; idx += 256) {
        const int d = idx >> 2, kk = (idx & 3) * 8;
        u16x8 v;
        #pragma unroll
        for (int i = 0; i < 8; ++i) v[i] = bf16bits(T[d][kk + i]);
        *(u16x8*)(Vt + ((size_t)bh * 96 + d) * SP + k0 + kk) = v;
    }
}

// ============================= MFMA flash attention =============================
// grid (21, B*H), 256 thr = 4 waves. 64 queries/block (16/wave), K/V tiles = 32.
// S^T trick: compute S^T = K Q^T so each thread owns ONE query (lane&15) and 8 keys
// -> key reductions are 7 in-thread ops + 2 shfl_xor(16,32); P packed as 2 b64 writes.
__global__ __launch_bounds__(256) void attn_mfma(const bf16* __restrict__ Qa,
    const bf16* __restrict__ Ka, const bf16* __restrict__ Vt,
    bf16* __restrict__ ab)
{
    __shared__ unsigned short Qs[64][104];   // 13312 B
    __shared__ unsigned short Ks[32][104];   //  6656 B
    __shared__ unsigned short Vs[96][40];    //  7680 B
    __shared__ unsigned short Ps[4][16][40]; //  5120 B

    const int tid = threadIdx.x;
    const int w = tid >> 6, l = tid & 63;
    const int lr = l & 15, kq = l >> 4;
    const int qblk = (int)gridDim.x - 1 - (int)blockIdx.x;   // big blocks first
    const int q0 = qblk * 64;
    const int bh = blockIdx.y;
    const int b = bh / H_, h = bh % H_;

    const bf16* Qg = Qa + (size_t)bh * SP * 96;
    const bf16* Kg = Ka + (size_t)bh * SP * 96;
    const bf16* Vg = Vt + (size_t)bh * 96 * SP;

    // ---- stage Q (64 rows x 96 cols) ----
    for (int c = tid; c < 768; c += 256) {
        const int row = c / 12, cc = c - row * 12;
        const int rg = q0 + row;
        u16x8 v = (u16x8)0;
        if (rg < SP) v = *(const u16x8*)(Qg + (size_t)rg * 96 + cc * 8);
        *(u16x8*)&Qs[row][cc * 8] = v;
    }
    __syncthreads();

    bf16x8 Qf[3];
    #pragma unroll
    for (int kf = 0; kf < 3; ++kf)
        Qf[kf] = *(const bf16x8*)&Qs[w * 16 + lr][kf * 32 + kq * 8];

    const int qw0 = q0 + w * 16;
    const int myq = qw0 + lr;                       // this thread's query
    const int wlq = (qw0 < S_) ? min(qw0 + 15, S_ - 1) : -1;
    const int lastq = min(q0 + 63, S_ - 1);
    const int ntiles = lastq / 32 + 1;

    f32x4 Of[6] = {};
    float mrun = -1e30f, lrun = 0.f;                // per-query (lr), replicated over kq

    for (int kt = 0; kt < ntiles; ++kt) {
        const int k0 = kt * 32;
        __syncthreads();
        // stage K tile (32 rows x 96 cols)
        for (int c = tid; c < 384; c += 256) {
            const int row = c / 12, cc = c - (c / 12) * 12;
            *(u16x8*)&Ks[row][cc * 8] = *(const u16x8*)(Kg + (size_t)(k0 + row) * 96 + cc * 8);
        }
        // stage V tile (96 dims x 32 keys)
        for (int c = tid; c < 384; c += 256) {
            const int d = c >> 2, kk = (c & 3) * 8;
            *(u16x8*)&Vs[d][kk] = *(const u16x8*)(Vg + (size_t)d * SP + k0 + kk);
        }
        __syncthreads();

        if (k0 > wlq) continue;   // wave-uniform skip; barriers above still executed

        // ---- S^T = K Q^T : thread holds keys {k0+16g+4kq+r} for query myq ----
        f32x4 sg0 = {0.f, 0.f, 0.f, 0.f}, sg1 = {0.f, 0.f, 0.f, 0.f};
        #pragma unroll
        for (int kf = 0; kf < 3; ++kf) {
            bf16x8 k0f = *(const bf16x8*)&Ks[lr][kf * 32 + kq * 8];
            bf16x8 k1f = *(const bf16x8*)&Ks[16 + lr][kf * 32 + kq * 8];
            sg0 = __builtin_amdgcn_mfma_f32_16x16x32_bf16(k0f, Qf[kf], sg0, 0, 0, 0);
            sg1 = __builtin_amdgcn_mfma_f32_16x16x32_bf16(k1f, Qf[kf], sg1, 0, 0, 0);
        }

        // ---- online softmax over keys (cheap: in-thread + 2 shfl) ----
        float e[8];
        float msub = -1e30f;
        #pragma unroll
        for (int r = 0; r < 4; ++r) {
            const int ka = k0 + 4 * kq + r;
            const int kb = ka + 16;
            const float a = (ka <= myq && ka < S_) ? sg0[r] : -1e30f;
            const float c = (kb <= myq && kb < S_) ? sg1[r] : -1e30f;
            e[r] = a; e[4 + r] = c;
            msub = fmaxf(msub, fmaxf(a, c));
        }
        msub = fmaxf(msub, __shfl_xor(msub, 16, 64));
        msub = fmaxf(msub, __shfl_xor(msub, 32, 64));
        const float nm = fmaxf(mrun, msub);
        const float resc = __expf(mrun - nm);
        mrun = nm;
        float ls = 0.f;
        #pragma unroll
        for (int i = 0; i < 8; ++i) {
            const float ev = (e[i] > -1e29f) ? __expf(e[i] - nm) : 0.f;
            e[i] = ev; ls += ev;
        }
        ls += __shfl_xor(ls, 16, 64);
        ls += __shfl_xor(ls, 32, 64);
        lrun = lrun * resc + ls;

        // ---- pack P (query=lr row, keys 4kq..4kq+3 and +16) : 2 x b64 writes ----
        ushort4 p0, p1;
        p0.x = bf16bits(e[0]); p0.y = bf16bits(e[1]); p0.z = bf16bits(e[2]); p0.w = bf16bits(e[3]);
        p1.x = bf16bits(e[4]); p1.y = bf16bits(e[5]); p1.z = bf16bits(e[6]); p1.w = bf16bits(e[7]);
        *(ushort4*)&Ps[w][lr][4 * kq]      = p0;
        *(ushort4*)&Ps[w][lr][16 + 4 * kq] = p1;

        // ---- rescale Of: resc indexed by lr, Of rows are queries 4kq+r ----
        float rf[4];
        #pragma unroll
        for (int r = 0; r < 4; ++r) rf[r] = __shfl(resc, 4 * kq + r, 16);
        #pragma unroll
        for (int c = 0; c < 6; ++c)
            #pragma unroll
            for (int r = 0; r < 4; ++r)
                Of[c][r] *= rf[r];

        // ---- O += P V ----
        bf16x8 Pf = *(const bf16x8*)&Ps[w][lr][kq * 8];
        #pragma unroll
        for (int c = 0; c < 6; ++c) {
            bf16x8 Vf = *(const bf16x8*)&Vs[16 * c + lr][kq * 8];
            Of[c] = __builtin_amdgcn_mfma_f32_16x16x32_bf16(Pf, Vf, Of[c], 0, 0, 0);
        }
    }

    // ---- epilogue ----
    const float invq = 1.0f / lrun;      // indexed by lr
    float inv[4];
    #pragma unroll
    for (int r = 0; r < 4; ++r) inv[r] = __shfl(invq, 4 * kq + r, 16);
    #pragma unroll
    for (int c = 0; c < 6; ++c) {
        const int dim = 16 * c + lr;
        if (dim >= DK_) continue;
        #pragma unroll
        for (int r = 0; r < 4; ++r) {
            const int qrow = qw0 + 4 * kq + r;
            if (qrow < S_)
                ab[(size_t)(b * S_ + qrow) * KP1 + h * DK_ + dim] =
                    __float2bfloat16(Of[c][r] * inv[r]);
        }
    }
}

// ============================= launch =============================
extern "C" void kernel_launch(void* const* d_in, const int* in_sizes, int n_in,
                              void* d_out, int out_size, void* d_ws, size_t ws_size,
                              hipStream_t stream)
{
    const float* x    = (const float*)d_in[0];
    const float* Wq   = (const float*)d_in[2];
    const float* bq   = (const float*)d_in[3];
    const float* Wk   = (const float*)d_in[4];
    const float* bk   = (const float*)d_in[5];
    const float* Wv   = (const float*)d_in[6];
    const float* bv   = (const float*)d_in[7];
    const float* Wo   = (const float*)d_in[8];
    const float* bo   = (const float*)d_in[9];
    const float* W1   = (const float*)d_in[10];
    const float* b1   = (const float*)d_in[11];
    const float* W2   = (const float*)d_in[12];
    const float* b2   = (const float*)d_in[13];
    const float* W3   = (const float*)d_in[14];
    const float* b3   = (const float*)d_in[15];
    const float* ln1g = (const float*)d_in[16];
    const float* ln1b = (const float*)d_in[17];
    const float* ln2g = (const float*)d_in[18];
    const float* ln2b = (const float*)d_in[19];
    const float* rc   = (const float*)d_in[20];
    const float* rs   = (const float*)d_in[21];
    float* out = (float*)d_out;

    char* wsb = (char*)d_ws;
    size_t off = 0;
    auto nxt = [&](size_t bytes) -> char* {
        char* p = wsb + off; off += (bytes + 255) & ~(size_t)255; return p;
    };
    bf16*  x2   = (bf16*)nxt((size_t)MROWS * KP1 * 2);
    bf16*  qkv  = (bf16*)nxt((size_t)MROWS * KP2 * 2);   // also hb later (KP2 >= QKVN)
    float* x1f  = (float*)nxt((size_t)MROWS * D_ * 4);   // Vt first, then x1
    bf16*  ab   = (bf16*)nxt((size_t)MROWS * KP1 * 2);
    bf16*  WqkvT= (bf16*)nxt((size_t)QKVN * KP1 * 2);
    bf16*  WoT  = (bf16*)nxt((size_t)D_ * KP1 * 2);
    bf16*  W1T  = (bf16*)nxt((size_t)FF_ * KP1 * 2);
    bf16*  W3T  = (bf16*)nxt((size_t)FF_ * KP1 * 2);
    bf16*  W2T  = (bf16*)nxt((size_t)D_ * KP2 * 2);
    bf16*  Qa   = (bf16*)nxt((size_t)B_ * H_ * SP * 96 * 2);
    bf16*  Ka   = (bf16*)nxt((size_t)B_ * H_ * SP * 96 * 2);
    float* bqkv = (float*)nxt((size_t)QKVN * 4);
    bf16*  Vt   = (bf16*)x1f;    // Vt dead before x1 is written (step 6)
    float* x1   = x1f;
    bf16*  hb   = qkv;           // qkv dead after vtrans; hb needs MROWS*KP2

    const dim3 blk(256);
    const dim3 gD(9, 82);
    const dim3 gF(26, 82);
    const int padN = MROWS * (KP1 - D_);

    zero_pads<<<(padN + 255) / 256, blk, 0, stream>>>(x2);
    zero_pads<<<(padN + 255) / 256, blk, 0, stream>>>(ab);
    bcat<<<(QKVN + 255) / 256, blk, 0, stream>>>(bq, bk, bv, bqkv);

    castT<<<dim3(34, 34),  blk, 0, stream>>>(Wq, WqkvT,                    D_, D_, KP1);
    castT<<<dim3(34, 34),  blk, 0, stream>>>(Wk, WqkvT + (size_t)D_ * KP1, D_, D_, KP1);
    castT<<<dim3(34, 34),  blk, 0, stream>>>(Wv, WqkvT + (size_t)2*D_*KP1, D_, D_, KP1);
    castT<<<dim3(34, 34),  blk, 0, stream>>>(Wo, WoT, D_, D_, KP1);
    castT<<<dim3(34, 102), blk, 0, stream>>>(W1, W1T, D_, FF_, KP1);
    castT<<<dim3(34, 102), blk, 0, stream>>>(W3, W3T, D_, FF_, KP1);
    castT<<<dim3(102, 34), blk, 0, stream>>>(W2, W2T, FF_, D_, KP2);

    // 1) LN1
    ln_kernel<<<MROWS, blk, 0, stream>>>(x, ln1g, ln1b, x2);
    // 2) merged QKV projection (bf16 out, row stride 3240)
    gemm_bf16<3><<<gF, blk, 0, stream>>>(x2, WqkvT, bqkv, nullptr, nullptr, qkv,
                                         MROWS, QKVN, KP1, QKVN, QKVN);
    // 3) RoPE + head layout
    rope_qk<<<dim3(SP, B_), blk, 0, stream>>>(qkv, rc, rs, Qa, Ka);
    // 4) V transpose
    vtrans<<<dim3(41, B_ * H_), blk, 0, stream>>>(qkv, Vt);
    // 5) MFMA flash attention -> ab
    attn_mfma<<<dim3(21, B_ * H_), blk, 0, stream>>>(Qa, Ka, Vt, ab);
    // 6) O-proj + residual -> x1
    gemm_bf16<1><<<gD, blk, 0, stream>>>(ab, WoT, bo, x, x1, nullptr, MROWS, D_, KP1, D_, D_);
    // 7) LN2
    ln_kernel<<<MROWS, blk, 0, stream>>>(x1, ln2g, ln2b, x2);
    // 8) h1 = x2@W1 + b1
    gemm_bf16<3><<<gF, blk, 0, stream>>>(x2, W1T, b1, nullptr, nullptr, hb, MROWS, FF_, KP1, KP2, KP2);
    // 9) h = silu(h1)*(x2@W3 + b3)
    gemm_bf16<2><<<gF, blk, 0, stream>>>(x2, W3T, b3, nullptr, nullptr, hb, MROWS, FF_, KP1, KP2, KP2);
    // 10) out = x1 + h@W2 + b2
    gemm_bf16<1><<<gD, blk, 0, stream>>>(hb, W2T, b2, x1, out, nullptr, MROWS, D_, KP2, D_, D_);
}